// Round 15
// baseline (553.752 us; speedup 1.0000x reference)
//
#include <hip/hip_runtime.h>

#define BB 8
#define CINC 64
#define COUTC 64
#define GCC 64
#define HH 320
#define WW 320
#define HP 322
#define WP 322
#define LEAK 0.2f
#define EPSB 1e-5f
#define HWSZ (HH*WW)
#define HWPSZ (HP*WP)

typedef unsigned short u16;
typedef __attribute__((ext_vector_type(8))) short short8v;   // 8 bf16
typedef __attribute__((ext_vector_type(16))) float f32x16;   // MFMA 32x32 acc
typedef __attribute__((ext_vector_type(4))) unsigned int u32x4;

static __device__ __forceinline__ u16 f2bf(float f) {
    unsigned u = __float_as_uint(f);
    u += 0x7fffu + ((u >> 16) & 1u);      // RNE
    return (u16)(u >> 16);
}
static __device__ __forceinline__ unsigned pk2bf(float a, float b) {
    return (unsigned)f2bf(a) | ((unsigned)f2bf(b) << 16);
}
// A-tile LDS swizzle (R6/R7-verified key)
static __device__ __forceinline__ unsigned swzA(int cc) {
    return (unsigned)((((cc >> 1) & 1) << 5) | (((cc >> 2) & 1) << 4));
}
// prd swizzle key: window-indexed (128B window id), bijective (R12-verified)
static __device__ __forceinline__ unsigned swzP(int px) {
    return ((unsigned)(px >> 2) & 7u) << 4;
}

// ---------------- K1: per-(b,g) mean of guidance ----------------
__global__ __launch_bounds__(256) void k_mean(const float* __restrict__ g,
                                              float* __restrict__ mean_g) {
    int row = blockIdx.x;                       // b*GC + gc
    const float4* p = (const float4*)(g + (size_t)row * HWSZ);
    float s = 0.f;
    for (int i = threadIdx.x; i < HWSZ / 4; i += 256) {
        float4 v = p[i];
        s += v.x + v.y + v.z + v.w;
    }
    #pragma unroll
    for (int off = 32; off; off >>= 1) s += __shfl_down(s, off);
    __shared__ float ls[4];
    if ((threadIdx.x & 63) == 0) ls[threadIdx.x >> 6] = s;
    __syncthreads();
    if (threadIdx.x == 0)
        mean_g[row] = (ls[0] + ls[1] + ls[2] + ls[3]) * (1.f / (float)HWSZ);
}

// ---------------- K2: kccB[b][o][c] bf16 ----------------
__global__ __launch_bounds__(256) void k_kcc(const float* __restrict__ mean_g,
                                             const float* __restrict__ w_cc,
                                             const float* __restrict__ b_cc,
                                             u16* __restrict__ kccB) {
    int idx = blockIdx.x * 256 + threadIdx.x;
    if (idx >= BB * COUTC * CINC) return;
    int b = idx >> 12;
    int j = idx & 4095;                  // o*64 + c
    const float* mg = mean_g + b * GCC;
    const float* wr = w_cc + (size_t)j * GCC;
    float s = b_cc[j];
    #pragma unroll
    for (int g = 0; g < GCC; ++g) s += mg[g] * wr[g];
    kccB[idx] = f2bf(s);
}

// ---------------- K3: wB = LDS image [gc][ks][tap][nj][l31][lhi][j] -------
__global__ __launch_bounds__(256) void k_wb(const float* __restrict__ w_kgl,
                                            u16* __restrict__ wB) {
    int idx = blockIdx.x * 256 + threadIdx.x;
    if (idx >= 36864) return;
    int j   = idx & 7;
    int lhi = (idx >> 3) & 1;
    int l   = (idx >> 4) & 31;
    int nj  = (idx >> 9) & 1;
    int t   = idx >> 10;          // (gc*2+ks)*9 + tap
    int tap = t % 9, gk = t / 9;
    int ks = gk & 1, gc = gk >> 1;
    int cout = nj * 32 + l;
    int g = gc * 32 + ks * 16 + lhi * 8 + j;
    wB[idx] = f2bf(w_kgl[((size_t)(cout * 64 + g)) * 9 + tap]);
}

// ---------------- K5: MFMA conv, A staged from RAW guid (R10-verified) ----
__global__ __launch_bounds__(384) void k_convm(const float* __restrict__ guid,
                                               const u16* __restrict__ wB,
                                               const float* __restrict__ b_kgl,
                                               u16* __restrict__ ker, int b0) {
    int xt = blockIdx.x, rt = blockIdx.y, bi = blockIdx.z;
    int bg = b0 + bi;
    int tid = threadIdx.x;
    int x0 = xt * 64, oy0 = rt * 6;
    __shared__ __align__(16) u16 ldsA[8 * 66 * 32];        // 33792 B
    __shared__ __align__(16) u16 ldsB[9 * 2 * 32 * 16];    // 18432 B

    int wv = tid >> 6, lane = tid & 63;
    int l31 = lane & 31, lhi = lane >> 5;
    f32x16 acc[2][2] = {};    // [s(px-half)][nj(cout-half)]

    for (int gc = 0; gc < 2; ++gc) {
        for (int ks = 0; ks < 2; ++ks) {
            if (gc | ks) __syncthreads();
            // ---- stage B: linear 18432 B copy
            const u16* bsrc = wB + (gc * 2 + ks) * 9216;
            #pragma unroll
            for (int k = 0; k < 3; ++k) {
                int i = tid + k * 384;
                *(u32x4*)(ldsB + (size_t)i * 8) = *(const u32x4*)(bsrc + (size_t)i * 8);
            }
            // ---- stage A from RAW guidance f32 (fused transpose + pack)
            if (ks == 0) {
                const float* gbase = guid + ((size_t)bg * 64 + gc * 32) * HWSZ;
                for (int i = tid; i < 544; i += 384) {
                    int qa = i % 17;
                    int rem = i / 17;
                    int go = rem & 3, rr = rem >> 2;
                    int iy = oy0 - 2 + rr;
                    int ix0 = x0 - 4 + 4 * qa;
                    union { float4 q; float f[4]; } va[8];
                    bool rowok = (iy >= 0) & (iy < HH);
                    if (rowok & (ix0 >= 0) & (ix0 + 3 < WW)) {
                        #pragma unroll
                        for (int j = 0; j < 8; ++j)
                            va[j].q = *(const float4*)(gbase + (size_t)(go * 8 + j) * HWSZ
                                                       + (size_t)iy * WW + ix0);
                    } else {
                        #pragma unroll
                        for (int j = 0; j < 8; ++j)
                            #pragma unroll
                            for (int t = 0; t < 4; ++t) {
                                int ix = ix0 + t;
                                va[j].f[t] = (rowok & (ix >= 0) & (ix < WW))
                                    ? gbase[(size_t)(go * 8 + j) * HWSZ + (size_t)iy * WW + ix]
                                    : 0.f;
                            }
                    }
                    #pragma unroll
                    for (int t = 0; t < 4; ++t) {
                        int cc = 4 * qa - 2 + t;
                        if (cc >= 0 && cc < 66) {
                            u32x4 wvv;
                            wvv[0] = pk2bf(va[0].f[t], va[1].f[t]);
                            wvv[1] = pk2bf(va[2].f[t], va[3].f[t]);
                            wvv[2] = pk2bf(va[4].f[t], va[5].f[t]);
                            wvv[3] = pk2bf(va[6].f[t], va[7].f[t]);
                            unsigned off = ((unsigned)((rr * 66 + cc) * 4 + go) * 16u)
                                           ^ swzA(cc);
                            *(u32x4*)((char*)ldsA + off) = wvv;
                        }
                    }
                }
            }
            __syncthreads();

            // ---- compute: 9 taps x 2 s x 2 nj (36 MFMA)
            for (int tap = 0; tap < 9; ++tap) {
                int di = tap / 3, dj = tap - di * 3;
                short8v Bf[2];
                #pragma unroll
                for (int nj = 0; nj < 2; ++nj)
                    Bf[nj] = *(const short8v*)(ldsB +
                        (((size_t)tap * 2 + nj) * 32 + l31) * 16 + lhi * 8);
                int rrow = wv + di;
                #pragma unroll
                for (int s = 0; s < 2; ++s) {
                    int cc = s * 32 + l31 + dj;
                    unsigned off = ((unsigned)((rrow * 66 + cc) * 4 + ks * 2 + lhi) * 16u)
                                   ^ swzA(cc);
                    short8v a = *(const short8v*)((const char*)ldsA + off);
                    acc[s][0] = __builtin_amdgcn_mfma_f32_32x32x16_bf16(a, Bf[0], acc[s][0], 0, 0, 0);
                    acc[s][1] = __builtin_amdgcn_mfma_f32_32x32x16_bf16(a, Bf[1], acc[s][1], 0, 0, 0);
                }
            }
        }
    }

    int oy = oy0 + wv;
    if (oy < HP) {
        float bias0 = b_kgl[l31], bias1 = b_kgl[32 + l31];
        u16* kout = ker + (size_t)bi * HWPSZ * GCC;
        int ckl = l31 >> 4, idx = l31 & 15;
        #pragma unroll
        for (int s = 0; s < 2; ++s)
            #pragma unroll
            for (int r = 0; r < 16; ++r) {
                int pxc = x0 + s * 32 + (r & 3) + 8 * (r >> 2) + 4 * lhi;
                if (pxc < WP) {
                    size_t pix = (size_t)oy * WP + pxc;
                    kout[((size_t)ckl * HWPSZ + pix) * 16 + idx]       = f2bf(acc[s][0][r] + bias0);
                    kout[((size_t)(2 + ckl) * HWPSZ + pix) * 16 + idx] = f2bf(acc[s][1][r] + bias1);
                }
            }
    }
}

// ---------------- K6: k_mix — 4-px window staging (3x fewer VMEM) ---------
// prd row stride padded 66->68 so a 4-px window never straddles a row.
// Unit = 4 px x 1 c-octet = one 128B window: 8 float4 data loads + 4 ker
// 16B loads. 204 units, single staging pass. Swizzle key constant per
// window by construction. Box-sum/MFMA/BN unchanged from R14.
__global__ __launch_bounds__(256) void k_mix(const float* __restrict__ data,
                                             const u16* __restrict__ ker,
                                             const u16* __restrict__ kccB,
                                             float* __restrict__ out,
                                             float* __restrict__ stats, int b0) {
    int xt = blockIdx.x, rt = blockIdx.y, bi = blockIdx.z;
    int b = b0 + bi;
    int w0 = xt * 64, oy0 = rt * 4;
    int tid = threadIdx.x, wv = tid >> 6, lane = tid & 63;
    int l31 = lane & 31, lhi = lane >> 5;

    __shared__ __align__(16) float prd[2 * 6 * 68 * 8];   // 26112 B (c2 stride 3264 f)
    __shared__ float bsum[64], bsq[64];

    if (tid < 64) { bsum[tid] = 0.f; bsq[tid] = 0.f; }

    const u16* kerb = ker + (size_t)bi * HWPSZ * GCC;
    const float* datb = data + (size_t)b * CINC * HWSZ;
    const u16* kcb  = kccB + (size_t)b * COUTC * CINC;

    f32x16 acc[2][2] = {};    // [nj(o-half)][s(px-half)]
    float pvr[4][8];          // staged products: 4 px x 8 c

    // unit decode (constant per thread)
    int uu = tid;
    int c2u = uu & 1;
    int rwu = uu >> 1;            // 0..101 when uu<204
    int rowu = rwu / 17, winu = rwu - rowu * 17;
    int col0 = winu * 4;
    int uk = oy0 + rowu;          // ker row
    int iu = uk - 1;

#define MIX_LOAD(CK)                                                          \
    if (uu < 204) {                                                           \
        bool rok = (iu >= 0) & (iu < HH);                                     \
        int iv0 = w0 + col0 - 1;                                              \
        if (rok & (winu < 16) & (iv0 >= 0) & (iv0 + 3 < WW)) {                \
            union { float4 q; float f[4]; } dq[8];                            \
            const float* dp = datb + ((size_t)(CK) * 16 + c2u * 8) * HWSZ     \
                              + (size_t)iu * WW + iv0;                        \
            _Pragma("unroll")                                                 \
            for (int j = 0; j < 8; ++j) dq[j].q = *(const float4*)(dp + (size_t)j * HWSZ); \
            const u16* kp = kerb + ((size_t)(CK) * HWPSZ + (size_t)uk * WP + w0 + col0) * 16 + c2u * 8; \
            _Pragma("unroll")                                                 \
            for (int t = 0; t < 4; ++t) {                                     \
                u32x4 kz = *(const u32x4*)(kp + t * 16);                      \
                _Pragma("unroll")                                             \
                for (int p = 0; p < 4; ++p) {                                 \
                    pvr[t][2 * p]     = __uint_as_float(kz[p] << 16) * dq[2 * p].f[t]; \
                    pvr[t][2 * p + 1] = __uint_as_float(kz[p] & 0xffff0000u) * dq[2 * p + 1].f[t]; \
                }                                                             \
            }                                                                 \
        } else {                                                              \
            _Pragma("unroll")                                                 \
            for (int t = 0; t < 4; ++t) {                                     \
                _Pragma("unroll")                                             \
                for (int j = 0; j < 8; ++j) pvr[t][j] = 0.f;                  \
                int col = col0 + t;                                           \
                int iv = w0 + col - 1;                                        \
                if (col < 66 && rok && iv >= 0 && iv < WW) {                  \
                    u32x4 kz = *(const u32x4*)(kerb + ((size_t)(CK) * HWPSZ + (size_t)uk * WP + w0 + col) * 16 + c2u * 8); \
                    const float* dp2 = datb + ((size_t)(CK) * 16 + c2u * 8) * HWSZ + (size_t)iu * WW + iv; \
                    _Pragma("unroll")                                         \
                    for (int p = 0; p < 4; ++p) {                             \
                        pvr[t][2 * p]     = __uint_as_float(kz[p] << 16) * dp2[(size_t)(2 * p) * HWSZ];       \
                        pvr[t][2 * p + 1] = __uint_as_float(kz[p] & 0xffff0000u) * dp2[(size_t)(2 * p + 1) * HWSZ]; \
                    }                                                         \
                }                                                             \
            }                                                                 \
        }                                                                     \
    }

    MIX_LOAD(0);

    #pragma unroll
    for (int ck = 0; ck < 4; ++ck) {
        if (ck) __syncthreads();                 // prev compute done reading prd
        // ---- write staged products -> prd (window-keyed XOR swizzle)
        if (uu < 204) {
            int pxp0 = rowu * 68 + col0;
            unsigned x = swzP(pxp0);             // constant over the window
            #pragma unroll
            for (int t = 0; t < 4; ++t) {
                unsigned fo = (unsigned)((c2u * 3264 + (pxp0 + t) * 8) * 4);
                *(float4*)((char*)prd + (fo ^ x))        = make_float4(pvr[t][0], pvr[t][1], pvr[t][2], pvr[t][3]);
                *(float4*)((char*)prd + ((fo + 16) ^ x)) = make_float4(pvr[t][4], pvr[t][5], pvr[t][6], pvr[t][7]);
            }
        }
        __syncthreads();
        if (ck < 3) MIX_LOAD(ck + 1);            // prefetch next chunk (T14)

        // ---- compute: box-sum from swizzled prd + MFMA mix
        short8v ka0 = *(const short8v*)(kcb + ((size_t)l31 * 64 + ck * 16 + lhi * 8));
        short8v ka1 = *(const short8v*)(kcb + ((size_t)(32 + l31) * 64 + ck * 16 + lhi * 8));

        #pragma unroll
        for (int s = 0; s < 2; ++s) {
            float x1v[8];
            #pragma unroll
            for (int j = 0; j < 8; ++j) x1v[j] = 0.f;
            #pragma unroll
            for (int di = 0; di < 3; ++di) {
                int row = wv + di;
                #pragma unroll
                for (int dj = 0; dj < 3; ++dj) {
                    int col = s * 32 + l31 + dj;
                    int px = row * 68 + col;
                    unsigned fo = (unsigned)((lhi * 3264 + px * 8) * 4);
                    unsigned x = swzP(px);
                    float4 a0 = *(const float4*)((const char*)prd + (fo ^ x));
                    float4 a1 = *(const float4*)((const char*)prd + ((fo + 16) ^ x));
                    x1v[0] += a0.x; x1v[1] += a0.y; x1v[2] += a0.z; x1v[3] += a0.w;
                    x1v[4] += a1.x; x1v[5] += a1.y; x1v[6] += a1.z; x1v[7] += a1.w;
                }
            }
            union { u16 h[8]; short8v v8; } xb;
            #pragma unroll
            for (int j = 0; j < 8; ++j) xb.h[j] = f2bf(x1v[j]);
            acc[0][s] = __builtin_amdgcn_mfma_f32_32x32x16_bf16(ka0, xb.v8, acc[0][s], 0, 0, 0);
            acc[1][s] = __builtin_amdgcn_mfma_f32_32x32x16_bf16(ka1, xb.v8, acc[1][s], 0, 0, 0);
        }
    }
#undef MIX_LOAD

    int oy = oy0 + wv;
    if (oy < HH) {
        #pragma unroll
        for (int nj = 0; nj < 2; ++nj)
            #pragma unroll
            for (int r = 0; r < 16; ++r) {
                int o = nj * 32 + (r & 3) + 8 * (r >> 2) + 4 * lhi;
                float v0 = acc[nj][0][r]; v0 = v0 > 0.f ? v0 : LEAK * v0;
                float v1 = acc[nj][1][r]; v1 = v1 > 0.f ? v1 : LEAK * v1;
                size_t rowb = ((size_t)(b * COUTC + o)) * HWSZ + (size_t)oy * WW + w0;
                out[rowb + l31]      = v0;
                out[rowb + 32 + l31] = v1;
                float ss = v0 + v1, qq = v0 * v0 + v1 * v1;
                #pragma unroll
                for (int off = 16; off; off >>= 1) {
                    ss += __shfl_xor(ss, off);
                    qq += __shfl_xor(qq, off);
                }
                if (l31 == 0) { atomicAdd(&bsum[o], ss); atomicAdd(&bsq[o], qq); }
            }
    }
    __syncthreads();
    int rep = (blockIdx.x + blockIdx.y * 5 + blockIdx.z * 3) & 7;
    if (tid < 64) {
        atomicAdd(&stats[rep * 128 + tid], bsum[tid]);
        atomicAdd(&stats[rep * 128 + 64 + tid], bsq[tid]);
    }
}

__global__ void k_fin(const float* __restrict__ stats,
                      const float* __restrict__ gamma, const float* __restrict__ beta,
                      float* __restrict__ scale, float* __restrict__ shift) {
    int o = threadIdx.x;
    float s = 0.f, q = 0.f;
    #pragma unroll
    for (int r = 0; r < 8; ++r) { s += stats[r * 128 + o]; q += stats[r * 128 + 64 + o]; }
    float n = (float)BB * (float)HWSZ;
    float mu = s / n;
    float var = q / n - mu * mu;
    float rs = rsqrtf(var + EPSB);
    float sc = rs * gamma[o];
    scale[o] = sc;
    shift[o] = beta[o] - mu * sc;
}

__global__ __launch_bounds__(256) void k_norm(float* __restrict__ x,
                                              const float* __restrict__ scale,
                                              const float* __restrict__ shift) {
    size_t i = (size_t)blockIdx.x * 256 + threadIdx.x;
    int ch = (int)((i * 4) / HWSZ) & 63;
    float4 v = ((float4*)x)[i];
    float sc = scale[ch], sh = shift[ch];
    v.x = v.x * sc + sh; v.y = v.y * sc + sh; v.z = v.z * sc + sh; v.w = v.w * sc + sh;
    ((float4*)x)[i] = v;
}

extern "C" void kernel_launch(void* const* d_in, const int* in_sizes, int n_in,
                              void* d_out, int out_size, void* d_ws, size_t ws_size,
                              hipStream_t stream) {
    const float* data  = (const float*)d_in[0];
    const float* guid  = (const float*)d_in[1];
    const float* w_kgl = (const float*)d_in[2];
    const float* b_kgl = (const float*)d_in[3];
    const float* w_cc  = (const float*)d_in[4];
    const float* b_cc  = (const float*)d_in[5];
    const float* gamma = (const float*)d_in[6];
    const float* beta  = (const float*)d_in[7];
    float* out = (float*)d_out;
    float* ws  = (float*)d_ws;

    // ws (f32): [mean_g 512][stats 8*128][scale 64][shift 64] = 1664
    // then u16: [kccB 32768][wB 36864][kerC bs*HWPSZ*64]
    float* mean_g = ws;
    float* stats  = ws + 512;
    float* scale  = stats + 1024;
    float* shift  = scale + 64;
    u16*   kccB   = (u16*)(ws + 1664);
    u16*   wB     = kccB + BB * 4096;
    u16*   kerC   = wB + 36864;

    size_t used_us = 1664 * 2 + BB * 4096 + 36864;
    size_t cap_us  = (ws_size / 2 > used_us) ? ws_size / 2 - used_us : 0;
    size_t per_b   = (size_t)HWPSZ * GCC;
    // bs=8: kerC = 106 MB total, L3-resident between k_convm and k_mix
    int bs = 8;
    while (bs > 1 && (size_t)bs * per_b > cap_us) bs >>= 1;

    hipMemsetAsync(stats, 0, 1024 * sizeof(float), stream);
    k_mean<<<BB * GCC, 256, 0, stream>>>(guid, mean_g);
    k_kcc<<<(BB * COUTC * CINC + 255) / 256, 256, 0, stream>>>(mean_g, w_cc, b_cc, kccB);
    k_wb<<<144, 256, 0, stream>>>(w_kgl, wB);

    for (int b0 = 0; b0 < BB; b0 += bs) {
        int nb = (BB - b0 < bs) ? BB - b0 : bs;
        k_convm<<<dim3(6, 54, nb), 384, 0, stream>>>(guid, wB, b_kgl, kerC, b0);
        k_mix<<<dim3(5, 80, nb), 256, 0, stream>>>(data, kerC, kccB, out, stats, b0);
    }
    k_fin<<<1, 64, 0, stream>>>(stats, gamma, beta, scale, shift);
    k_norm<<<(out_size / 4 + 255) / 256, 256, 0, stream>>>(out, scale, shift);
}